// Round 3
// baseline (393.453 us; speedup 1.0000x reference)
//
#include <hip/hip_runtime.h>
#include <math.h>
#include <stdint.h>

#define B_ 32
#define N_ 1024
#define D_ 256
#define K_ 8
#define CAND 12

typedef unsigned short u16;
typedef unsigned int u32;
typedef __attribute__((ext_vector_type(8))) short s16x8;   // 8 bf16 (4 VGPRs)
typedef __attribute__((ext_vector_type(16))) float f32x16; // 32x32 accumulator

__device__ inline u16 f2bf(float f) {               // RNE float->bf16 bits
    uint32_t u = __float_as_uint(f);
    return (u16)((u + 0x7fffu + ((u >> 16) & 1u)) >> 16);
}
__device__ inline float bf2f(u16 h) { return __uint_as_float(((uint32_t)h) << 16); }
__device__ inline u32 umax32(u32 a, u32 b) { return a > b ? a : b; }
__device__ inline u32 umin32(u32 a, u32 b) { return a < b ? a : b; }

// ------------- Kernel 1: fp64 inverse norms + normalized bf16 hi/lo -------------
__global__ __launch_bounds__(256) void prep_kernel(const float* __restrict__ tok,
                                                   double* __restrict__ invn,
                                                   u16* __restrict__ xhi,
                                                   u16* __restrict__ xlo) {
    const int tid = threadIdx.x;
    const int wave = tid >> 6, lane = tid & 63;
    const int row = blockIdx.x * 4 + wave;          // 32768 rows
    const float4 v = *reinterpret_cast<const float4*>(tok + (size_t)row * D_ + lane * 4);
    double s = (double)v.x * v.x + (double)v.y * v.y +
               (double)v.z * v.z + (double)v.w * v.w;
    #pragma unroll
    for (int off = 32; off > 0; off >>= 1) s += __shfl_xor(s, off, 64);
    const double inv = 1.0 / (sqrt(s) + 1e-8);
    if (lane == 0) invn[row] = inv;
    const float x0 = (float)(v.x * inv), x1 = (float)(v.y * inv),
                x2 = (float)(v.z * inv), x3 = (float)(v.w * inv);
    ushort4 h, l;
    h.x = f2bf(x0); l.x = f2bf(x0 - bf2f(h.x));
    h.y = f2bf(x1); l.y = f2bf(x1 - bf2f(h.y));
    h.z = f2bf(x2); l.z = f2bf(x2 - bf2f(h.z));
    h.w = f2bf(x3); l.w = f2bf(x3 - bf2f(h.w));
    *reinterpret_cast<ushort4*>(xhi + (size_t)row * D_ + lane * 4) = h;
    *reinterpret_cast<ushort4*>(xlo + (size_t)row * D_ + lane * 4) = l;
}

// ------------- Kernel 2: MFMA sim + in-register top-12 + fp64 rescore -------------
// R3 structure: NO LDS / NO barriers in the main loop.
//  * A fragments (hi+lo, 4kc x 4ks) live in registers for the whole kernel (128 VGPR).
//  * B fragments load DIRECTLY global->VGPR: per-lane addr = row*512B + half*16B with
//    constant offsets kc*128+ks*32 folding into the load's imm offset. Working set per
//    wave per jt = 32 rows x 512B x 2 = 32KB (L1-resident; mq-pair waves share lines);
//    B panel is L2-resident per XCD (proven: FETCH 37MB). Un-swizzled global fragment
//    == swizzled-LDS logical fragment (XOR write o XOR read = id) -> identical math.
//  * Waves fully independent: latencies hidden by cross-wave overlap (scan VALU of one
//    wave vs MFMA/loads of the other), no lockstep convoy.
//  * Two acc chains (bh*ah | bl*ah + bh*al) halve the acc dependency depth; summed in
//    the scan. Top-12 scan: packed u32 keys (24-bit monotone fp32 | (jt,reg) code),
//    branchless v_max/v_min insert chain.
// LDS: only epilogue scratch (keysL 12KB + mj 3KB + dv 6KB = 21.3KB).
__global__ __launch_bounds__(256, 2) void sim_topk_kernel(const u16* __restrict__ Xhi,
                                                          const u16* __restrict__ Xlo,
                                                          const float* __restrict__ tok,
                                                          const double* __restrict__ invn,
                                                          int* __restrict__ topk) {
    __shared__ u32    keysL[64 * 4 * CAND];
    __shared__ int    mj[64 * CAND];
    __shared__ double dv[64 * CAND];

    // XCD batch-affinity swizzle: each XCD owns 4 whole batches -> B panel L2-resident
    const int id    = blockIdx.x;            // 0..511
    const int chunk = id >> 3;               // 0..63
    const int b  = (id & 7) * 4 + (chunk >> 4);
    const int i0 = (chunk & 15) * 64;

    const int tid = threadIdx.x;
    const int w = tid >> 6, lane = tid & 63;
    const int mq = w >> 1, nq = w & 1;       // 2x2 wave grid of 32x32 tiles
    const int half = lane >> 5;
    const int il = lane & 31;

    const char* XhiB = (const char*)(Xhi + (size_t)b * N_ * D_);
    const char* XloB = (const char*)(Xlo + (size_t)b * N_ * D_);

    // per-lane byte offsets: row*512 + half*16 (fragment k-chunk = ks*2+half)
    const size_t aoff = (size_t)(i0 + mq * 32 + il) * 512 + half * 16;
    const size_t boff = (size_t)(nq * 32 + il) * 512 + half * 16;

    // ---- A fragments (hi+lo, 4kc x 4ks) -> registers, direct from global ----
    s16x8 Ah[4][4], Al[4][4];                // 128 VGPRs, static-indexed only
    {
        const char* pAh = XhiB + aoff;
        const char* pAl = XloB + aoff;
        #pragma unroll
        for (int kc = 0; kc < 4; ++kc)
            #pragma unroll
            for (int ks = 0; ks < 4; ++ks) {
                Ah[kc][ks] = *(const s16x8*)(pAh + kc * 128 + ks * 32);
                Al[kc][ks] = *(const s16x8*)(pAl + kc * 128 + ks * 32);
            }
    }

    const int diag_jt = i0 >> 6;             // jt where j-tile == i-strip
    u32 keys[CAND];
    #pragma unroll
    for (int c = 0; c < CAND; ++c) keys[c] = 0u;   // real sims always pack > 0

    for (int jt = 0; jt < 16; ++jt) {
        const char* pBh = XhiB + (size_t)jt * 32768 + boff;
        const char* pBl = XloB + (size_t)jt * 32768 + boff;
        f32x16 acc1, acc2;
        #pragma unroll
        for (int c = 0; c < 16; ++c) { acc1[c] = 0.0f; acc2[c] = 0.0f; }

        #pragma unroll
        for (int kc = 0; kc < 4; ++kc) {
            s16x8 bh[4], bl[4];
            #pragma unroll
            for (int ks = 0; ks < 4; ++ks) {
                bh[ks] = *(const s16x8*)(pBh + kc * 128 + ks * 32);
                bl[ks] = *(const s16x8*)(pBl + kc * 128 + ks * 32);
            }
            #pragma unroll
            for (int ks = 0; ks < 4; ++ks) {
                acc1 = __builtin_amdgcn_mfma_f32_32x32x16_bf16(bh[ks], Ah[kc][ks], acc1, 0, 0, 0);
                acc2 = __builtin_amdgcn_mfma_f32_32x32x16_bf16(bl[ks], Ah[kc][ks], acc2, 0, 0, 0);
                acc2 = __builtin_amdgcn_mfma_f32_32x32x16_bf16(bh[ks], Al[kc][ks], acc2, 0, 0, 0);
            }
        }

        // in-register scan (16 j-candidates of row i0+mq*32+il)
        const u32 codebase = (u32)(jt << 4);
        const bool diag = (jt == diag_jt) && (mq == nq);
        #pragma unroll
        for (int rg = 0; rg < 16; ++rg) {
            const float sv = acc1[rg] + acc2[rg];
            const u32 u = __float_as_uint(sv);
            const u32 mono = u ^ ((u32)(((int)u) >> 31) | 0x80000000u); // order-preserving
            u32 key = (mono & 0xFFFFFF00u) | (codebase + (u32)rg);
            if (diag && ((rg & 3) + 8 * (rg >> 2) + 4 * half == il)) key = 0u; // kill self
            u32 t = key;
            #pragma unroll
            for (int c = 0; c < CAND; ++c) {         // branchless sorted insert (desc)
                const u32 hi = umax32(keys[c], t);
                t = umin32(keys[c], t);
                keys[c] = hi;
            }
        }
    }

    // publish per-slot sorted candidate lists
    {
        const int r = mq * 32 + il;
        const int s = nq * 2 + half;
        u32* dst = keysL + (r * 4 + s) * CAND;
        #pragma unroll
        for (int c = 0; c < CAND; ++c) dst[c] = keys[c];
    }
    __syncthreads();

    // 4-way merge of sorted key lists -> top-12 per row, decode j from code byte
    if (tid < 64) {
        const u32* kl = keysL + tid * (4 * CAND);
        int p0 = 0, p1 = 0, p2 = 0, p3 = 0;
        #pragma unroll
        for (int o = 0; o < CAND; ++o) {
            const u32 k0v = kl[p0];
            const u32 k1v = kl[CAND + p1];
            const u32 k2v = kl[2 * CAND + p2];
            const u32 k3v = kl[3 * CAND + p3];
            int bg = 0; u32 bv = k0v;
            if (k1v > bv) { bv = k1v; bg = 1; }
            if (k2v > bv) { bv = k2v; bg = 2; }
            if (k3v > bv) { bv = k3v; bg = 3; }
            const int code = (int)(bv & 0xFFu);
            const int jtv = code >> 4, rg = code & 15;
            // j = jt*64 + nq*32 + (rg&3)+8*(rg>>2)+4*half; slot bg: nq=bg>>1, half=bg&1
            mj[tid * CAND + o] = jtv * 64 + (bg >> 1) * 32 + (rg & 3) + 8 * (rg >> 2)
                                 + 4 * (bg & 1);
            p0 += (bg == 0); p1 += (bg == 1); p2 += (bg == 2); p3 += (bg == 3);
        }
    }
    __syncthreads();

    // fp64 rescore, parallel over 3 groups of 4 candidates
    const float*  tokB = tok  + (size_t)b * N_ * D_;
    const double* invB = invn + b * N_;
    if (tid < 192) {
        const int r = tid & 63, g = tid >> 6;
        const int gi = i0 + r;
        const float* qi = tokB + (size_t)gi * D_;
        const double di = invB[gi];
        #pragma unroll 1
        for (int cc = 0; cc < 4; ++cc) {
            const int c = g * 4 + cc;
            const int j = mj[r * CAND + c];
            const float* qj = tokB + (size_t)j * D_;
            double s = 0.0;
            for (int d = 0; d < D_; d += 4) {
                const float4 x = *reinterpret_cast<const float4*>(qi + d);
                const float4 y = *reinterpret_cast<const float4*>(qj + d);
                s += (double)x.x * y.x + (double)x.y * y.y +
                     (double)x.z * y.z + (double)x.w * y.w;
            }
            dv[r * CAND + c] = s * di * invB[j];
        }
    }
    __syncthreads();

    // exact top-8 by fp64 rank (ties -> lower index, matching lax.top_k)
    if (tid < 64) {
        const int out_base = (b * N_ + i0 + tid) * K_;
        #pragma unroll 1
        for (int c = 0; c < CAND; ++c) {
            const double dc = dv[tid * CAND + c]; const int jc = mj[tid * CAND + c];
            int rank = 0;
            #pragma unroll 1
            for (int c2 = 0; c2 < CAND; ++c2) {
                if (c2 == c) continue;
                const double d2 = dv[tid * CAND + c2]; const int j2 = mj[tid * CAND + c2];
                if (d2 > dc || (d2 == dc && j2 < jc)) ++rank;
            }
            if (rank < K_) topk[out_base + rank] = jc;
        }
    }
}

// ------------- Kernel 3: mutual filter + scatter 1.0 -------------
__global__ __launch_bounds__(256) void mutual_kernel(const int* __restrict__ topk,
                                                     float* __restrict__ out) {
    const int gid = blockIdx.x * 256 + threadIdx.x;   // 32768*8 threads
    const int row = gid >> 3, s = gid & 7;
    const int j = topk[row * K_ + s];
    const int i = row & (N_ - 1);
    const int* tj = topk + ((row & ~(N_ - 1)) + j) * K_;
    bool m = false;
    #pragma unroll
    for (int u = 0; u < K_; ++u) m = m || (tj[u] == i);
    if (m) out[(size_t)row * N_ + j] = 1.0f;
}

extern "C" void kernel_launch(void* const* d_in, const int* in_sizes, int n_in,
                              void* d_out, int out_size, void* d_ws, size_t ws_size,
                              hipStream_t stream) {
    const float* tok = (const float*)d_in[0];
    float* out = (float*)d_out;
    double* invn = (double*)d_ws;                                  // 256 KB
    int* topk = (int*)((char*)d_ws + (size_t)B_ * N_ * sizeof(double)); // 1 MB
    // bf16 hi/lo scratch lives in d_out (32 MB of 128 MB) until memset
    u16* xhi = (u16*)d_out;
    u16* xlo = xhi + (size_t)B_ * N_ * D_;

    prep_kernel<<<dim3(B_ * N_ / 4), 256, 0, stream>>>(tok, invn, xhi, xlo);
    sim_topk_kernel<<<dim3(512), 256, 0, stream>>>(xhi, xlo, tok, invn, topk);
    hipMemsetAsync(d_out, 0, (size_t)out_size * sizeof(float), stream);
    mutual_kernel<<<dim3(B_ * N_ * K_ / 256), 256, 0, stream>>>(topk, out);
}

// Round 4
// 380.827 us; speedup vs baseline: 1.0332x; 1.0332x over previous
//
#include <hip/hip_runtime.h>
#include <math.h>
#include <stdint.h>

#define B_ 32
#define N_ 1024
#define D_ 256
#define K_ 8
#define CAND 12

typedef unsigned short u16;
typedef unsigned int u32;
typedef __attribute__((ext_vector_type(8))) short s16x8;   // 8 bf16 (4 VGPRs)
typedef __attribute__((ext_vector_type(16))) float f32x16; // 32x32 accumulator

__device__ inline void cp16(const void* g, void* l) {
    // async global->LDS, 16B/lane; LDS dest = wave-uniform base + lane*16
    __builtin_amdgcn_global_load_lds((const __attribute__((address_space(1))) void*)g,
                                     (__attribute__((address_space(3))) void*)l, 16, 0, 0);
}

__device__ inline u16 f2bf(float f) {               // RNE float->bf16 bits
    uint32_t u = __float_as_uint(f);
    return (u16)((u + 0x7fffu + ((u >> 16) & 1u)) >> 16);
}
__device__ inline float bf2f(u16 h) { return __uint_as_float(((uint32_t)h) << 16); }
__device__ inline u32 umax32(u32 a, u32 b) { return a > b ? a : b; }
__device__ inline u32 umin32(u32 a, u32 b) { return a < b ? a : b; }

// ------------- Kernel 1: fp64 inverse norms + normalized bf16 hi/lo -------------
__global__ __launch_bounds__(256) void prep_kernel(const float* __restrict__ tok,
                                                   double* __restrict__ invn,
                                                   u16* __restrict__ xhi,
                                                   u16* __restrict__ xlo) {
    const int tid = threadIdx.x;
    const int wave = tid >> 6, lane = tid & 63;
    const int row = blockIdx.x * 4 + wave;          // 32768 rows
    const float4 v = *reinterpret_cast<const float4*>(tok + (size_t)row * D_ + lane * 4);
    double s = (double)v.x * v.x + (double)v.y * v.y +
               (double)v.z * v.z + (double)v.w * v.w;
    #pragma unroll
    for (int off = 32; off > 0; off >>= 1) s += __shfl_xor(s, off, 64);
    const double inv = 1.0 / (sqrt(s) + 1e-8);
    if (lane == 0) invn[row] = inv;
    const float x0 = (float)(v.x * inv), x1 = (float)(v.y * inv),
                x2 = (float)(v.z * inv), x3 = (float)(v.w * inv);
    ushort4 h, l;
    h.x = f2bf(x0); l.x = f2bf(x0 - bf2f(h.x));
    h.y = f2bf(x1); l.y = f2bf(x1 - bf2f(h.y));
    h.z = f2bf(x2); l.z = f2bf(x2 - bf2f(h.z));
    h.w = f2bf(x3); l.w = f2bf(x3 - bf2f(h.w));
    *reinterpret_cast<ushort4*>(xhi + (size_t)row * D_ + lane * 4) = h;
    *reinterpret_cast<ushort4*>(xlo + (size_t)row * D_ + lane * 4) = l;
}

// ------------- Kernel 2: MFMA sim + in-register top-12 per j-half -------------
// R4: occupancy 2->4 blocks/CU. Grid 1024 = 32 batches x 16 i-strips x 2 j-halves;
// each block: 64 i-rows x 8 jt tiles. LDS = 32KB (2-buffer, 1-round-ahead counted
// vmcnt(4) pipeline); epilogue keysL aliases dead tiles. A fragments in registers
// (VGPR 108 <= 128 -> 4 waves/SIMD). Per-row sorted top-12 (key,j) of THIS j-half
// goes to global scratch; merge+rescore kernel combines the two halves.
__global__ __launch_bounds__(256, 4) void sim_topk_kernel(const u16* __restrict__ Xhi,
                                                          const u16* __restrict__ Xlo,
                                                          u32* __restrict__ candk,
                                                          int* __restrict__ candj) {
    __shared__ __align__(16) char smem[32768];
    char* tiles = smem;                       // 2 bufs x (Bh 8KB | Bl 8KB)
    u32*  keysL = (u32*)smem;                 // aliases tiles after main loop

    // XCD batch-affinity swizzle: id&7 = XCD; each XCD owns 4 whole batches.
    const int id    = blockIdx.x;             // 0..1023
    const int chunk = id >> 3;                // 0..127
    const int b   = (id & 7) * 4 + (chunk >> 5);
    const int rem = chunk & 31;
    const int i0  = (rem >> 1) * 64;
    const int jh  = rem & 1;                  // j-half: jt in [jh*8, jh*8+8)

    const int tid = threadIdx.x;
    const int w = tid >> 6, lane = tid & 63;
    const int mq = w >> 1, nq = w & 1;        // 2x2 wave grid of 32x32 tiles
    const int half = lane >> 5;
    const int il = lane & 31;

    const u16* XhiB = Xhi + (size_t)b * N_ * D_;
    const u16* XloB = Xlo + (size_t)b * N_ * D_;

    // staging role: wave 0/1 -> hi rows 0-31/32-63, wave 2/3 -> lo rows 0-31/32-63
    const int srr = lane >> 3, spp = lane & 7;       // row-in-group, chunk-pos
    const u16* ssrc = (w < 2) ? XhiB : XloB;
    const int  sgoff = (spp ^ srr) * 8;              // gathered source chunk (u16 units)
    const int  srow  = (w & 1) * 32 + srr;           // + t*8
    char* const sbase = tiles + ((w < 2) ? 0 : 8192) + (w & 1) * 4096;

    // fragment rows (fixed per lane)
    const int ra = mq * 32 + il;
    const int rb = nq * 32 + il;
    const int xa = ra & 7, xb = rb & 7;              // XOR keys

    // ---- prologue: load A fragments (hi+lo, 4kc x 4ks) into registers ----
    s16x8 Ahf[4][4], Alf[4][4];                      // 128 VGPRs, static-indexed only
    #pragma unroll
    for (int kc = 0; kc < 4; ++kc) {
        __syncthreads();                             // tiles free for overwrite
        #pragma unroll
        for (int t = 0; t < 4; ++t) {
            const int rr = srow + t * 8;
            cp16(ssrc + (size_t)(i0 + rr) * D_ + kc * 64 + sgoff, sbase + t * 1024);
        }
        __syncthreads();                             // vmcnt(0) drain ok in prologue
        #pragma unroll
        for (int ks = 0; ks < 4; ++ks) {
            const int ca = ((ks * 2 + half) ^ xa) * 16;
            Ahf[kc][ks] = *(const s16x8*)(tiles +        ra * 128 + ca);
            Alf[kc][ks] = *(const s16x8*)(tiles + 8192 + ra * 128 + ca);
        }
    }
    __syncthreads();                                 // A reads done; clean vmcnt slate

    auto STAGE_B = [&](int round, int bufn) {        // round = (jt-jh*8)*4 + kc
        const int j0n = (jh * 8 + (round >> 2)) * 64;
        const int kcn = round & 3;
        char* bdst = sbase + bufn * 16384;
        #pragma unroll
        for (int t = 0; t < 4; ++t) {
            const int rr = srow + t * 8;
            cp16(ssrc + (size_t)(j0n + rr) * D_ + kcn * 64 + sgoff, bdst + t * 1024);
        }
    };

    const int diag_jt = i0 >> 6;                     // jt where j-tile == i-strip
    u32 keys[CAND];
    #pragma unroll
    for (int c = 0; c < CAND; ++c) keys[c] = 0u;     // real sims always pack > 0

    STAGE_B(0, 0);

    for (int lt = 0; lt < 8; ++lt) {                 // local jt
        const int jt = jh * 8 + lt;
        f32x16 acc;
        #pragma unroll
        for (int c = 0; c < 16; ++c) acc[c] = 0.0f;

        #pragma unroll
        for (int kc = 0; kc < 4; ++kc) {
            const int r = lt * 4 + kc;
            const int cur = r & 1;
            // issue stage r+1 into the other buf; wait for round r's loads
            if (r < 31) {
                STAGE_B(r + 1, cur ^ 1);
                asm volatile("s_waitcnt vmcnt(4)" ::: "memory");
            } else {
                asm volatile("s_waitcnt vmcnt(0)" ::: "memory");
            }
            __builtin_amdgcn_s_barrier();            // B1: all waves' round-r loads landed
            __builtin_amdgcn_sched_barrier(0);       // pin ds_reads below the barrier
            const char* bb = tiles + cur * 16384;
            #pragma unroll
            for (int ks = 0; ks < 4; ++ks) {
                const int cb = ((ks * 2 + half) ^ xb) * 16;
                const s16x8 bh = *(const s16x8*)(bb +        rb * 128 + cb);
                const s16x8 bl = *(const s16x8*)(bb + 8192 + rb * 128 + cb);
                acc = __builtin_amdgcn_mfma_f32_32x32x16_bf16(bh, Ahf[kc][ks], acc, 0, 0, 0);
                acc = __builtin_amdgcn_mfma_f32_32x32x16_bf16(bl, Ahf[kc][ks], acc, 0, 0, 0);
                acc = __builtin_amdgcn_mfma_f32_32x32x16_bf16(bh, Alf[kc][ks], acc, 0, 0, 0);
            }
            __builtin_amdgcn_sched_barrier(0);       // pin reads/MFMA above B2
            __builtin_amdgcn_s_barrier();            // B2: buf[cur] free for stage r+2
        }

        // in-register scan (16 j-candidates of row i0+mq*32+il); overlaps next loads
        const u32 codebase = (u32)(jt << 4);         // jt<16, rg<16 -> 8-bit code
        const bool diag = (jt == diag_jt) && (mq == nq);
        #pragma unroll
        for (int rg = 0; rg < 16; ++rg) {
            const u32 u = __float_as_uint(acc[rg]);
            const u32 mono = u ^ ((u32)(((int)u) >> 31) | 0x80000000u); // order-preserving
            u32 key = (mono & 0xFFFFFF00u) | (codebase + (u32)rg);
            if (diag && ((rg & 3) + 8 * (rg >> 2) + 4 * half == il)) key = 0u; // kill self
            u32 t = key;
            #pragma unroll
            for (int c = 0; c < CAND; ++c) {         // branchless sorted insert (desc)
                const u32 hi = umax32(keys[c], t);
                t = umin32(keys[c], t);
                keys[c] = hi;
            }
        }
    }

    __syncthreads();                                 // tiles dead -> alias keysL
    {
        const int r = mq * 32 + il;
        const int s = nq * 2 + half;
        u32* dst = keysL + (r * 4 + s) * CAND;
        #pragma unroll
        for (int c = 0; c < CAND; ++c) dst[c] = keys[c];
    }
    __syncthreads();

    // 4-way merge of sorted slot lists -> this half's top-12 per row -> global scratch
    if (tid < 64) {
        const u32* kl = keysL + tid * (4 * CAND);
        const size_t base = ((size_t)(b * N_ + i0 + tid) * 2 + jh) * CAND;
        int p0 = 0, p1 = 0, p2 = 0, p3 = 0;
        #pragma unroll
        for (int o = 0; o < CAND; ++o) {
            const u32 k0v = kl[p0];
            const u32 k1v = kl[CAND + p1];
            const u32 k2v = kl[2 * CAND + p2];
            const u32 k3v = kl[3 * CAND + p3];
            int bg = 0; u32 bv = k0v;
            if (k1v > bv) { bv = k1v; bg = 1; }
            if (k2v > bv) { bv = k2v; bg = 2; }
            if (k3v > bv) { bv = k3v; bg = 3; }
            const int code = (int)(bv & 0xFFu);
            const int jtv = code >> 4, rg = code & 15;
            // j = jt*64 + nq*32 + (rg&3)+8*(rg>>2)+4*half; slot bg: nq=bg>>1, half=bg&1
            candk[base + o] = bv;
            candj[base + o] = jtv * 64 + (bg >> 1) * 32 + (rg & 3) + 8 * (rg >> 2)
                              + 4 * (bg & 1);
            p0 += (bg == 0); p1 += (bg == 1); p2 += (bg == 2); p3 += (bg == 3);
        }
    }
}

// ------------- Kernel 2b: merge halves + fp64 rescore + exact top-8 -------------
__global__ __launch_bounds__(256) void merge_rescore_kernel(const u32* __restrict__ candk,
                                                            const int* __restrict__ candj,
                                                            const float* __restrict__ tok,
                                                            const double* __restrict__ invn,
                                                            int* __restrict__ topk) {
    __shared__ int    mj[64 * CAND];
    __shared__ double dv[64 * CAND];
    const int tid = threadIdx.x;
    const int R0 = blockIdx.x * 64;                  // global row base (b*N + i)

    if (tid < 64) {                                  // 2-way merge of sorted halves
        const size_t base = (size_t)(R0 + tid) * 2 * CAND;
        int p0 = 0, p1 = 0;
        #pragma unroll
        for (int o = 0; o < CAND; ++o) {
            const u32 k0 = candk[base + p0];
            const u32 k1 = candk[base + CAND + p1];
            if (k0 >= k1) { mj[tid * CAND + o] = candj[base + p0];        ++p0; }
            else          { mj[tid * CAND + o] = candj[base + CAND + p1]; ++p1; }
        }
    }
    __syncthreads();

    const int b = R0 >> 10;                          // N_=1024 divides R0
    if (tid < 192) {
        const int r = tid & 63, g = tid >> 6;
        const float* qi = tok + (size_t)(R0 + r) * D_;
        const double di = invn[R0 + r];
        #pragma unroll 1
        for (int cc = 0; cc < 4; ++cc) {
            const int c = g * 4 + cc;
            const int j = mj[r * CAND + c];
            const float* qj = tok + (size_t)(b * N_ + j) * D_;
            double s = 0.0;
            for (int d = 0; d < D_; d += 4) {
                const float4 x = *reinterpret_cast<const float4*>(qi + d);
                const float4 y = *reinterpret_cast<const float4*>(qj + d);
                s += (double)x.x * y.x + (double)x.y * y.y +
                     (double)x.z * y.z + (double)x.w * y.w;
            }
            dv[r * CAND + c] = s * di * invn[b * N_ + j];
        }
    }
    __syncthreads();

    // exact top-8 by fp64 rank (ties -> lower index, matching lax.top_k)
    if (tid < 64) {
        const int out_base = (R0 + tid) * K_;
        #pragma unroll 1
        for (int c = 0; c < CAND; ++c) {
            const double dc = dv[tid * CAND + c]; const int jc = mj[tid * CAND + c];
            int rank = 0;
            #pragma unroll 1
            for (int c2 = 0; c2 < CAND; ++c2) {
                if (c2 == c) continue;
                const double d2 = dv[tid * CAND + c2]; const int j2 = mj[tid * CAND + c2];
                if (d2 > dc || (d2 == dc && j2 < jc)) ++rank;
            }
            if (rank < K_) topk[out_base + rank] = jc;
        }
    }
}

// ------------- Kernel 3: mutual filter + scatter 1.0 -------------
__global__ __launch_bounds__(256) void mutual_kernel(const int* __restrict__ topk,
                                                     float* __restrict__ out) {
    const int gid = blockIdx.x * 256 + threadIdx.x;   // 32768*8 threads
    const int row = gid >> 3, s = gid & 7;
    const int j = topk[row * K_ + s];
    const int i = row & (N_ - 1);
    const int* tj = topk + ((row & ~(N_ - 1)) + j) * K_;
    bool m = false;
    #pragma unroll
    for (int u = 0; u < K_; ++u) m = m || (tj[u] == i);
    if (m) out[(size_t)row * N_ + j] = 1.0f;
}

extern "C" void kernel_launch(void* const* d_in, const int* in_sizes, int n_in,
                              void* d_out, int out_size, void* d_ws, size_t ws_size,
                              hipStream_t stream) {
    const float* tok = (const float*)d_in[0];
    float* out = (float*)d_out;
    double* invn = (double*)d_ws;                                  // 256 KB
    int* topk = (int*)((char*)d_ws + (size_t)B_ * N_ * sizeof(double)); // 1 MB
    // scratch lives in d_out (128 MB) until memset:
    //   [0,16MB) xhi, [16,32MB) xlo, [32,35MB) candk, [35,38MB) candj
    u16* xhi = (u16*)d_out;
    u16* xlo = xhi + (size_t)B_ * N_ * D_;
    u32* candk = (u32*)((char*)d_out + (size_t)32 * 1024 * 1024);
    int* candj = (int*)((char*)d_out + (size_t)35 * 1024 * 1024);

    prep_kernel<<<dim3(B_ * N_ / 4), 256, 0, stream>>>(tok, invn, xhi, xlo);
    sim_topk_kernel<<<dim3(1024), 256, 0, stream>>>(xhi, xlo, candk, candj);
    merge_rescore_kernel<<<dim3(B_ * N_ / 64), 256, 0, stream>>>(candk, candj, tok, invn, topk);
    hipMemsetAsync(d_out, 0, (size_t)out_size * sizeof(float), stream);
    mutual_kernel<<<dim3(B_ * N_ * K_ / 256), 256, 0, stream>>>(topk, out);
}

// Round 5
// 371.104 us; speedup vs baseline: 1.0602x; 1.0262x over previous
//
#include <hip/hip_runtime.h>
#include <math.h>
#include <stdint.h>

#define B_ 32
#define N_ 1024
#define D_ 256
#define K_ 8
#define CAND 12

typedef unsigned short u16;
typedef unsigned int u32;
typedef __attribute__((ext_vector_type(8))) short s16x8;   // 8 bf16 (4 VGPRs)
typedef __attribute__((ext_vector_type(16))) float f32x16; // 32x32 accumulator

__device__ inline void cp16(const void* g, void* l) {
    // async global->LDS, 16B/lane; LDS dest = wave-uniform base + lane*16
    __builtin_amdgcn_global_load_lds((const __attribute__((address_space(1))) void*)g,
                                     (__attribute__((address_space(3))) void*)l, 16, 0, 0);
}

__device__ inline u16 f2bf(float f) {               // RNE float->bf16 bits
    uint32_t u = __float_as_uint(f);
    return (u16)((u + 0x7fffu + ((u >> 16) & 1u)) >> 16);
}
__device__ inline float bf2f(u16 h) { return __uint_as_float(((uint32_t)h) << 16); }
__device__ inline u32 umax32(u32 a, u32 b) { return a > b ? a : b; }
__device__ inline u32 umin32(u32 a, u32 b) { return a < b ? a : b; }

// ------------- Kernel 1: fp64 inverse norms + normalized bf16 hi/lo -------------
__global__ __launch_bounds__(256) void prep_kernel(const float* __restrict__ tok,
                                                   double* __restrict__ invn,
                                                   u16* __restrict__ xhi,
                                                   u16* __restrict__ xlo) {
    const int tid = threadIdx.x;
    const int wave = tid >> 6, lane = tid & 63;
    const int row = blockIdx.x * 4 + wave;          // 32768 rows
    const float4 v = *reinterpret_cast<const float4*>(tok + (size_t)row * D_ + lane * 4);
    double s = (double)v.x * v.x + (double)v.y * v.y +
               (double)v.z * v.z + (double)v.w * v.w;
    #pragma unroll
    for (int off = 32; off > 0; off >>= 1) s += __shfl_xor(s, off, 64);
    const double inv = 1.0 / (sqrt(s) + 1e-8);
    if (lane == 0) invn[row] = inv;
    const float x0 = (float)(v.x * inv), x1 = (float)(v.y * inv),
                x2 = (float)(v.z * inv), x3 = (float)(v.w * inv);
    ushort4 h, l;
    h.x = f2bf(x0); l.x = f2bf(x0 - bf2f(h.x));
    h.y = f2bf(x1); l.y = f2bf(x1 - bf2f(h.y));
    h.z = f2bf(x2); l.z = f2bf(x2 - bf2f(h.z));
    h.w = f2bf(x3); l.w = f2bf(x3 - bf2f(h.w));
    *reinterpret_cast<ushort4*>(xhi + (size_t)row * D_ + lane * 4) = h;
    *reinterpret_cast<ushort4*>(xlo + (size_t)row * D_ + lane * 4) = l;
}

// ------------- Kernel 2: MFMA sim + in-register top-12 per j-half -------------
// R4 structure (kept): 4 blocks/CU. Grid 1024 = 32 batches x 16 i-strips x 2 j-halves;
// each block: 64 i-rows x 8 jt tiles. LDS = 32KB (2-buffer, 1-round-ahead counted
// vmcnt(4) pipeline); epilogue keysL aliases dead tiles. A fragments in registers.
// Per-row sorted top-12 (key,j) of THIS j-half -> global scratch.
__global__ __launch_bounds__(256, 4) void sim_topk_kernel(const u16* __restrict__ Xhi,
                                                          const u16* __restrict__ Xlo,
                                                          u32* __restrict__ candk,
                                                          int* __restrict__ candj) {
    __shared__ __align__(16) char smem[32768];
    char* tiles = smem;                       // 2 bufs x (Bh 8KB | Bl 8KB)
    u32*  keysL = (u32*)smem;                 // aliases tiles after main loop

    // XCD batch-affinity swizzle: id&7 = XCD; each XCD owns 4 whole batches.
    const int id    = blockIdx.x;             // 0..1023
    const int chunk = id >> 3;                // 0..127
    const int b   = (id & 7) * 4 + (chunk >> 5);
    const int rem = chunk & 31;
    const int i0  = (rem >> 1) * 64;
    const int jh  = rem & 1;                  // j-half: jt in [jh*8, jh*8+8)

    const int tid = threadIdx.x;
    const int w = tid >> 6, lane = tid & 63;
    const int mq = w >> 1, nq = w & 1;        // 2x2 wave grid of 32x32 tiles
    const int half = lane >> 5;
    const int il = lane & 31;

    const u16* XhiB = Xhi + (size_t)b * N_ * D_;
    const u16* XloB = Xlo + (size_t)b * N_ * D_;

    // staging role: wave 0/1 -> hi rows 0-31/32-63, wave 2/3 -> lo rows 0-31/32-63
    const int srr = lane >> 3, spp = lane & 7;       // row-in-group, chunk-pos
    const u16* ssrc = (w < 2) ? XhiB : XloB;
    const int  sgoff = (spp ^ srr) * 8;              // gathered source chunk (u16 units)
    const int  srow  = (w & 1) * 32 + srr;           // + t*8
    char* const sbase = tiles + ((w < 2) ? 0 : 8192) + (w & 1) * 4096;

    // fragment rows (fixed per lane)
    const int ra = mq * 32 + il;
    const int rb = nq * 32 + il;
    const int xa = ra & 7, xb = rb & 7;              // XOR keys

    // ---- prologue: load A fragments (hi+lo, 4kc x 4ks) into registers ----
    s16x8 Ahf[4][4], Alf[4][4];                      // 128 VGPRs, static-indexed only
    #pragma unroll
    for (int kc = 0; kc < 4; ++kc) {
        __syncthreads();                             // tiles free for overwrite
        #pragma unroll
        for (int t = 0; t < 4; ++t) {
            const int rr = srow + t * 8;
            cp16(ssrc + (size_t)(i0 + rr) * D_ + kc * 64 + sgoff, sbase + t * 1024);
        }
        __syncthreads();                             // vmcnt(0) drain ok in prologue
        #pragma unroll
        for (int ks = 0; ks < 4; ++ks) {
            const int ca = ((ks * 2 + half) ^ xa) * 16;
            Ahf[kc][ks] = *(const s16x8*)(tiles +        ra * 128 + ca);
            Alf[kc][ks] = *(const s16x8*)(tiles + 8192 + ra * 128 + ca);
        }
    }
    __syncthreads();                                 // A reads done; clean vmcnt slate

    auto STAGE_B = [&](int round, int bufn) {        // round = (jt-jh*8)*4 + kc
        const int j0n = (jh * 8 + (round >> 2)) * 64;
        const int kcn = round & 3;
        char* bdst = sbase + bufn * 16384;
        #pragma unroll
        for (int t = 0; t < 4; ++t) {
            const int rr = srow + t * 8;
            cp16(ssrc + (size_t)(j0n + rr) * D_ + kcn * 64 + sgoff, bdst + t * 1024);
        }
    };

    const int diag_jt = i0 >> 6;                     // jt where j-tile == i-strip
    u32 keys[CAND];
    #pragma unroll
    for (int c = 0; c < CAND; ++c) keys[c] = 0u;     // real sims always pack > 0

    STAGE_B(0, 0);

    for (int lt = 0; lt < 8; ++lt) {                 // local jt
        const int jt = jh * 8 + lt;
        f32x16 acc;
        #pragma unroll
        for (int c = 0; c < 16; ++c) acc[c] = 0.0f;

        #pragma unroll
        for (int kc = 0; kc < 4; ++kc) {
            const int r = lt * 4 + kc;
            const int cur = r & 1;
            // issue stage r+1 into the other buf; wait for round r's loads
            if (r < 31) {
                STAGE_B(r + 1, cur ^ 1);
                asm volatile("s_waitcnt vmcnt(4)" ::: "memory");
            } else {
                asm volatile("s_waitcnt vmcnt(0)" ::: "memory");
            }
            __builtin_amdgcn_s_barrier();            // B1: all waves' round-r loads landed
            __builtin_amdgcn_sched_barrier(0);       // pin ds_reads below the barrier
            const char* bb = tiles + cur * 16384;
            #pragma unroll
            for (int ks = 0; ks < 4; ++ks) {
                const int cb = ((ks * 2 + half) ^ xb) * 16;
                const s16x8 bh = *(const s16x8*)(bb +        rb * 128 + cb);
                const s16x8 bl = *(const s16x8*)(bb + 8192 + rb * 128 + cb);
                acc = __builtin_amdgcn_mfma_f32_32x32x16_bf16(bh, Ahf[kc][ks], acc, 0, 0, 0);
                acc = __builtin_amdgcn_mfma_f32_32x32x16_bf16(bl, Ahf[kc][ks], acc, 0, 0, 0);
                acc = __builtin_amdgcn_mfma_f32_32x32x16_bf16(bh, Alf[kc][ks], acc, 0, 0, 0);
            }
            __builtin_amdgcn_sched_barrier(0);       // pin reads/MFMA above B2
            __builtin_amdgcn_s_barrier();            // B2: buf[cur] free for stage r+2
        }

        // in-register scan (16 j-candidates of row i0+mq*32+il); overlaps next loads
        const u32 codebase = (u32)(jt << 4);         // jt<16, rg<16 -> 8-bit code
        const bool diag = (jt == diag_jt) && (mq == nq);
        #pragma unroll
        for (int rg = 0; rg < 16; ++rg) {
            const u32 u = __float_as_uint(acc[rg]);
            const u32 mono = u ^ ((u32)(((int)u) >> 31) | 0x80000000u); // order-preserving
            u32 key = (mono & 0xFFFFFF00u) | (codebase + (u32)rg);
            if (diag && ((rg & 3) + 8 * (rg >> 2) + 4 * half == il)) key = 0u; // kill self
            u32 t = key;
            #pragma unroll
            for (int c = 0; c < CAND; ++c) {         // branchless sorted insert (desc)
                const u32 hi = umax32(keys[c], t);
                t = umin32(keys[c], t);
                keys[c] = hi;
            }
        }
    }

    __syncthreads();                                 // tiles dead -> alias keysL
    {
        const int r = mq * 32 + il;
        const int s = nq * 2 + half;
        u32* dst = keysL + (r * 4 + s) * CAND;
        #pragma unroll
        for (int c = 0; c < CAND; ++c) dst[c] = keys[c];
    }
    __syncthreads();

    // 4-way merge of sorted slot lists -> this half's top-12 per row -> global scratch
    if (tid < 64) {
        const u32* kl = keysL + tid * (4 * CAND);
        const size_t base = ((size_t)(b * N_ + i0 + tid) * 2 + jh) * CAND;
        int p0 = 0, p1 = 0, p2 = 0, p3 = 0;
        #pragma unroll
        for (int o = 0; o < CAND; ++o) {
            const u32 k0v = kl[p0];
            const u32 k1v = kl[CAND + p1];
            const u32 k2v = kl[2 * CAND + p2];
            const u32 k3v = kl[3 * CAND + p3];
            int bg = 0; u32 bv = k0v;
            if (k1v > bv) { bv = k1v; bg = 1; }
            if (k2v > bv) { bv = k2v; bg = 2; }
            if (k3v > bv) { bv = k3v; bg = 3; }
            const int code = (int)(bv & 0xFFu);
            const int jtv = code >> 4, rg = code & 15;
            // j = jt*64 + nq*32 + (rg&3)+8*(rg>>2)+4*half; slot bg: nq=bg>>1, half=bg&1
            candk[base + o] = bv;
            candj[base + o] = jtv * 64 + (bg >> 1) * 32 + (rg & 3) + 8 * (rg >> 2)
                              + 4 * (bg & 1);
            p0 += (bg == 0); p1 += (bg == 1); p2 += (bg == 2); p3 += (bg == 3);
        }
    }
}

// ------------- Kernel 2b: merge halves + fp64 rescore + exact top-8 -------------
// R5: XCD batch-affinity swizzle (same as sim/R1 fix) -- without it each batch's
// fp32 token panel was pulled by ~7 XCDs (FETCH 217MB, 117us). With it, each XCD
// reads only its 4 owned batches (panels L2-resident). Rescore uses all 256 threads
// (4 groups x 3 candidates).
__global__ __launch_bounds__(256) void merge_rescore_kernel(const u32* __restrict__ candk,
                                                            const int* __restrict__ candj,
                                                            const float* __restrict__ tok,
                                                            const double* __restrict__ invn,
                                                            int* __restrict__ topk) {
    __shared__ int    mj[64 * CAND];
    __shared__ double dv[64 * CAND];
    const int tid = threadIdx.x;

    // XCD batch-affinity swizzle: id&7 = XCD; each XCD owns 4 whole batches.
    const int id    = blockIdx.x;                    // 0..511
    const int chunk = id >> 3;                       // 0..63
    const int b     = (id & 7) * 4 + (chunk >> 4);
    const int i0    = (chunk & 15) * 64;
    const int R0    = b * N_ + i0;                   // global row base

    if (tid < 64) {                                  // 2-way merge of sorted halves
        const size_t base = (size_t)(R0 + tid) * 2 * CAND;
        int p0 = 0, p1 = 0;
        #pragma unroll
        for (int o = 0; o < CAND; ++o) {
            const u32 k0 = candk[base + p0];
            const u32 k1 = candk[base + CAND + p1];
            if (k0 >= k1) { mj[tid * CAND + o] = candj[base + p0];        ++p0; }
            else          { mj[tid * CAND + o] = candj[base + CAND + p1]; ++p1; }
        }
    }
    __syncthreads();

    // fp64 rescore: 4 groups x 3 candidates, all 256 threads
    {
        const int r = tid & 63, g = tid >> 6;
        const float* qi = tok + (size_t)(R0 + r) * D_;
        const double di = invn[R0 + r];
        #pragma unroll 1
        for (int cc = 0; cc < 3; ++cc) {
            const int c = g * 3 + cc;
            const int j = mj[r * CAND + c];
            const float* qj = tok + (size_t)(b * N_ + j) * D_;
            double s = 0.0;
            for (int d = 0; d < D_; d += 4) {
                const float4 x = *reinterpret_cast<const float4*>(qi + d);
                const float4 y = *reinterpret_cast<const float4*>(qj + d);
                s += (double)x.x * y.x + (double)x.y * y.y +
                     (double)x.z * y.z + (double)x.w * y.w;
            }
            dv[r * CAND + c] = s * di * invn[b * N_ + j];
        }
    }
    __syncthreads();

    // exact top-8 by fp64 rank (ties -> lower index, matching lax.top_k)
    if (tid < 64) {
        const int out_base = (R0 + tid) * K_;
        #pragma unroll 1
        for (int c = 0; c < CAND; ++c) {
            const double dc = dv[tid * CAND + c]; const int jc = mj[tid * CAND + c];
            int rank = 0;
            #pragma unroll 1
            for (int c2 = 0; c2 < CAND; ++c2) {
                if (c2 == c) continue;
                const double d2 = dv[tid * CAND + c2]; const int j2 = mj[tid * CAND + c2];
                if (d2 > dc || (d2 == dc && j2 < jc)) ++rank;
            }
            if (rank < K_) topk[out_base + rank] = jc;
        }
    }
}

// ------------- Kernel 3: mutual filter + scatter 1.0 -------------
__global__ __launch_bounds__(256) void mutual_kernel(const int* __restrict__ topk,
                                                     float* __restrict__ out) {
    const int gid = blockIdx.x * 256 + threadIdx.x;   // 32768*8 threads
    const int row = gid >> 3, s = gid & 7;
    const int j = topk[row * K_ + s];
    const int i = row & (N_ - 1);
    const int* tj = topk + ((row & ~(N_ - 1)) + j) * K_;
    bool m = false;
    #pragma unroll
    for (int u = 0; u < K_; ++u) m = m || (tj[u] == i);
    if (m) out[(size_t)row * N_ + j] = 1.0f;
}

extern "C" void kernel_launch(void* const* d_in, const int* in_sizes, int n_in,
                              void* d_out, int out_size, void* d_ws, size_t ws_size,
                              hipStream_t stream) {
    const float* tok = (const float*)d_in[0];
    float* out = (float*)d_out;
    double* invn = (double*)d_ws;                                  // 256 KB
    int* topk = (int*)((char*)d_ws + (size_t)B_ * N_ * sizeof(double)); // 1 MB
    // scratch lives in d_out (128 MB) until memset:
    //   [0,16MB) xhi, [16,32MB) xlo, [32,35MB) candk, [35,38MB) candj
    u16* xhi = (u16*)d_out;
    u16* xlo = xhi + (size_t)B_ * N_ * D_;
    u32* candk = (u32*)((char*)d_out + (size_t)32 * 1024 * 1024);
    int* candj = (int*)((char*)d_out + (size_t)35 * 1024 * 1024);

    prep_kernel<<<dim3(B_ * N_ / 4), 256, 0, stream>>>(tok, invn, xhi, xlo);
    sim_topk_kernel<<<dim3(1024), 256, 0, stream>>>(xhi, xlo, candk, candj);
    merge_rescore_kernel<<<dim3(B_ * N_ / 64), 256, 0, stream>>>(candk, candj, tok, invn, topk);
    hipMemsetAsync(d_out, 0, (size_t)out_size * sizeof(float), stream);
    mutual_kernel<<<dim3(B_ * N_ * K_ / 256), 256, 0, stream>>>(topk, out);
}

// Round 6
// 301.315 us; speedup vs baseline: 1.3058x; 1.2316x over previous
//
#include <hip/hip_runtime.h>
#include <math.h>
#include <stdint.h>

#define B_ 32
#define N_ 1024
#define D_ 256
#define K_ 8
#define CAND 12

typedef unsigned short u16;
typedef unsigned int u32;
typedef __attribute__((ext_vector_type(8))) short s16x8;   // 8 bf16 (4 VGPRs)
typedef __attribute__((ext_vector_type(16))) float f32x16; // 32x32 accumulator

__device__ inline void cp16(const void* g, void* l) {
    // async global->LDS, 16B/lane; LDS dest = wave-uniform base + lane*16
    __builtin_amdgcn_global_load_lds((const __attribute__((address_space(1))) void*)g,
                                     (__attribute__((address_space(3))) void*)l, 16, 0, 0);
}

__device__ inline u16 f2bf(float f) {               // RNE float->bf16 bits
    uint32_t u = __float_as_uint(f);
    return (u16)((u + 0x7fffu + ((u >> 16) & 1u)) >> 16);
}
__device__ inline float bf2f(u16 h) { return __uint_as_float(((uint32_t)h) << 16); }
__device__ inline u32 umax32(u32 a, u32 b) { return a > b ? a : b; }
__device__ inline u32 umin32(u32 a, u32 b) { return a < b ? a : b; }

// ------------- Kernel 1: fp64 inverse norms + normalized bf16 hi/lo -------------
__global__ __launch_bounds__(256) void prep_kernel(const float* __restrict__ tok,
                                                   double* __restrict__ invn,
                                                   u16* __restrict__ xhi,
                                                   u16* __restrict__ xlo) {
    const int tid = threadIdx.x;
    const int wave = tid >> 6, lane = tid & 63;
    const int row = blockIdx.x * 4 + wave;          // 32768 rows
    const float4 v = *reinterpret_cast<const float4*>(tok + (size_t)row * D_ + lane * 4);
    double s = (double)v.x * v.x + (double)v.y * v.y +
               (double)v.z * v.z + (double)v.w * v.w;
    #pragma unroll
    for (int off = 32; off > 0; off >>= 1) s += __shfl_xor(s, off, 64);
    const double inv = 1.0 / (sqrt(s) + 1e-8);
    if (lane == 0) invn[row] = inv;
    const float x0 = (float)(v.x * inv), x1 = (float)(v.y * inv),
                x2 = (float)(v.z * inv), x3 = (float)(v.w * inv);
    ushort4 h, l;
    h.x = f2bf(x0); l.x = f2bf(x0 - bf2f(h.x));
    h.y = f2bf(x1); l.y = f2bf(x1 - bf2f(h.y));
    h.z = f2bf(x2); l.z = f2bf(x2 - bf2f(h.z));
    h.w = f2bf(x3); l.w = f2bf(x3 - bf2f(h.w));
    *reinterpret_cast<ushort4*>(xhi + (size_t)row * D_ + lane * 4) = h;
    *reinterpret_cast<ushort4*>(xlo + (size_t)row * D_ + lane * 4) = l;
}

// ------------- Kernel 2: MFMA sim + in-register top-12 per j-half -------------
// R4 structure kept. R6 change: __launch_bounds__(256, 3) NOT (256,4) -- the 4-waves/EU
// bound capped the allocator at ~128 VGPR + 128 AGPR/wave, below the ~144 AGPR-class
// demand (A frags 128 + acc 16) -> scratch spill (R5: VGPR_Count 64, FETCH 270MB,
// WRITE 72MB of spill traffic). At 3 waves/EU the budget is ~170/170: no spill, and
// occupancy is set by actual allocation at runtime (>=3 blocks/CU).
__global__ __launch_bounds__(256, 3) void sim_topk_kernel(const u16* __restrict__ Xhi,
                                                          const u16* __restrict__ Xlo,
                                                          u32* __restrict__ candk,
                                                          int* __restrict__ candj) {
    __shared__ __align__(16) char smem[32768];
    char* tiles = smem;                       // 2 bufs x (Bh 8KB | Bl 8KB)
    u32*  keysL = (u32*)smem;                 // aliases tiles after main loop

    // XCD batch-affinity swizzle: id&7 = XCD; each XCD owns 4 whole batches.
    const int id    = blockIdx.x;             // 0..1023
    const int chunk = id >> 3;                // 0..127
    const int b   = (id & 7) * 4 + (chunk >> 5);
    const int rem = chunk & 31;
    const int i0  = (rem >> 1) * 64;
    const int jh  = rem & 1;                  // j-half: jt in [jh*8, jh*8+8)

    const int tid = threadIdx.x;
    const int w = tid >> 6, lane = tid & 63;
    const int mq = w >> 1, nq = w & 1;        // 2x2 wave grid of 32x32 tiles
    const int half = lane >> 5;
    const int il = lane & 31;

    const u16* XhiB = Xhi + (size_t)b * N_ * D_;
    const u16* XloB = Xlo + (size_t)b * N_ * D_;

    // staging role: wave 0/1 -> hi rows 0-31/32-63, wave 2/3 -> lo rows 0-31/32-63
    const int srr = lane >> 3, spp = lane & 7;       // row-in-group, chunk-pos
    const u16* ssrc = (w < 2) ? XhiB : XloB;
    const int  sgoff = (spp ^ srr) * 8;              // gathered source chunk (u16 units)
    const int  srow  = (w & 1) * 32 + srr;           // + t*8
    char* const sbase = tiles + ((w < 2) ? 0 : 8192) + (w & 1) * 4096;

    // fragment rows (fixed per lane)
    const int ra = mq * 32 + il;
    const int rb = nq * 32 + il;
    const int xa = ra & 7, xb = rb & 7;              // XOR keys

    // ---- prologue: load A fragments (hi+lo, 4kc x 4ks) into registers ----
    s16x8 Ahf[4][4], Alf[4][4];                      // 128 regs, static-indexed only
    #pragma unroll
    for (int kc = 0; kc < 4; ++kc) {
        __syncthreads();                             // tiles free for overwrite
        #pragma unroll
        for (int t = 0; t < 4; ++t) {
            const int rr = srow + t * 8;
            cp16(ssrc + (size_t)(i0 + rr) * D_ + kc * 64 + sgoff, sbase + t * 1024);
        }
        __syncthreads();                             // vmcnt(0) drain ok in prologue
        #pragma unroll
        for (int ks = 0; ks < 4; ++ks) {
            const int ca = ((ks * 2 + half) ^ xa) * 16;
            Ahf[kc][ks] = *(const s16x8*)(tiles +        ra * 128 + ca);
            Alf[kc][ks] = *(const s16x8*)(tiles + 8192 + ra * 128 + ca);
        }
    }
    __syncthreads();                                 // A reads done; clean vmcnt slate

    auto STAGE_B = [&](int round, int bufn) {        // round = (jt-jh*8)*4 + kc
        const int j0n = (jh * 8 + (round >> 2)) * 64;
        const int kcn = round & 3;
        char* bdst = sbase + bufn * 16384;
        #pragma unroll
        for (int t = 0; t < 4; ++t) {
            const int rr = srow + t * 8;
            cp16(ssrc + (size_t)(j0n + rr) * D_ + kcn * 64 + sgoff, bdst + t * 1024);
        }
    };

    const int diag_jt = i0 >> 6;                     // jt where j-tile == i-strip
    u32 keys[CAND];
    #pragma unroll
    for (int c = 0; c < CAND; ++c) keys[c] = 0u;     // real sims always pack > 0

    STAGE_B(0, 0);

    for (int lt = 0; lt < 8; ++lt) {                 // local jt
        const int jt = jh * 8 + lt;
        f32x16 acc;
        #pragma unroll
        for (int c = 0; c < 16; ++c) acc[c] = 0.0f;

        #pragma unroll
        for (int kc = 0; kc < 4; ++kc) {
            const int r = lt * 4 + kc;
            const int cur = r & 1;
            // issue stage r+1 into the other buf; wait for round r's loads
            if (r < 31) {
                STAGE_B(r + 1, cur ^ 1);
                asm volatile("s_waitcnt vmcnt(4)" ::: "memory");
            } else {
                asm volatile("s_waitcnt vmcnt(0)" ::: "memory");
            }
            __builtin_amdgcn_s_barrier();            // B1: all waves' round-r loads landed
            __builtin_amdgcn_sched_barrier(0);       // pin ds_reads below the barrier
            const char* bb = tiles + cur * 16384;
            #pragma unroll
            for (int ks = 0; ks < 4; ++ks) {
                const int cb = ((ks * 2 + half) ^ xb) * 16;
                const s16x8 bh = *(const s16x8*)(bb +        rb * 128 + cb);
                const s16x8 bl = *(const s16x8*)(bb + 8192 + rb * 128 + cb);
                acc = __builtin_amdgcn_mfma_f32_32x32x16_bf16(bh, Ahf[kc][ks], acc, 0, 0, 0);
                acc = __builtin_amdgcn_mfma_f32_32x32x16_bf16(bl, Ahf[kc][ks], acc, 0, 0, 0);
                acc = __builtin_amdgcn_mfma_f32_32x32x16_bf16(bh, Alf[kc][ks], acc, 0, 0, 0);
            }
            __builtin_amdgcn_sched_barrier(0);       // pin reads/MFMA above B2
            __builtin_amdgcn_s_barrier();            // B2: buf[cur] free for stage r+2
        }

        // in-register scan (16 j-candidates of row i0+mq*32+il); overlaps next loads
        const u32 codebase = (u32)(jt << 4);         // jt<16, rg<16 -> 8-bit code
        const bool diag = (jt == diag_jt) && (mq == nq);
        #pragma unroll
        for (int rg = 0; rg < 16; ++rg) {
            const u32 u = __float_as_uint(acc[rg]);
            const u32 mono = u ^ ((u32)(((int)u) >> 31) | 0x80000000u); // order-preserving
            u32 key = (mono & 0xFFFFFF00u) | (codebase + (u32)rg);
            if (diag && ((rg & 3) + 8 * (rg >> 2) + 4 * half == il)) key = 0u; // kill self
            u32 t = key;
            #pragma unroll
            for (int c = 0; c < CAND; ++c) {         // branchless sorted insert (desc)
                const u32 hi = umax32(keys[c], t);
                t = umin32(keys[c], t);
                keys[c] = hi;
            }
        }
    }

    __syncthreads();                                 // tiles dead -> alias keysL
    {
        const int r = mq * 32 + il;
        const int s = nq * 2 + half;
        u32* dst = keysL + (r * 4 + s) * CAND;
        #pragma unroll
        for (int c = 0; c < CAND; ++c) dst[c] = keys[c];
    }
    __syncthreads();

    // 4-way merge of sorted slot lists -> this half's top-12 per row -> global scratch
    if (tid < 64) {
        const u32* kl = keysL + tid * (4 * CAND);
        const size_t base = ((size_t)(b * N_ + i0 + tid) * 2 + jh) * CAND;
        int p0 = 0, p1 = 0, p2 = 0, p3 = 0;
        #pragma unroll
        for (int o = 0; o < CAND; ++o) {
            const u32 k0v = kl[p0];
            const u32 k1v = kl[CAND + p1];
            const u32 k2v = kl[2 * CAND + p2];
            const u32 k3v = kl[3 * CAND + p3];
            int bg = 0; u32 bv = k0v;
            if (k1v > bv) { bv = k1v; bg = 1; }
            if (k2v > bv) { bv = k2v; bg = 2; }
            if (k3v > bv) { bv = k3v; bg = 3; }
            const int code = (int)(bv & 0xFFu);
            const int jtv = code >> 4, rg = code & 15;
            // j = jt*64 + nq*32 + (rg&3)+8*(rg>>2)+4*half; slot bg: nq=bg>>1, half=bg&1
            candk[base + o] = bv;
            candj[base + o] = jtv * 64 + (bg >> 1) * 32 + (rg & 3) + 8 * (rg >> 2)
                              + 4 * (bg & 1);
            p0 += (bg == 0); p1 += (bg == 1); p2 += (bg == 2); p3 += (bg == 3);
        }
    }
}

// ------------- Kernel 2b: merge halves + fp64 rescore + exact top-8 -------------
// R6: coalesced quad-per-dot rescore. Old layout had each THREAD walk a row (wave
// touches 64 rows/iter: 16B used per 64B line, 512-deep fp64 chain). Now 4 lanes
// share one dot: lane ql reads float4 at k*64+ql*16 (full 64B lines for qi AND qj),
// __shfl_xor quad reduce; 512 threads (16 waves/CU at grid 512). XCD batch-affinity
// swizzle kept (R5: FETCH 217MB->L2-resident).
__global__ __launch_bounds__(512) void merge_rescore_kernel(const u32* __restrict__ candk,
                                                            const int* __restrict__ candj,
                                                            const float* __restrict__ tok,
                                                            const double* __restrict__ invn,
                                                            int* __restrict__ topk) {
    __shared__ int    mj[64 * CAND];
    __shared__ double dv[64 * CAND];
    const int tid = threadIdx.x;

    // XCD batch-affinity swizzle: id&7 = XCD; each XCD owns 4 whole batches.
    const int id    = blockIdx.x;                    // 0..511
    const int chunk = id >> 3;                       // 0..63
    const int b     = (id & 7) * 4 + (chunk >> 4);
    const int i0    = (chunk & 15) * 64;
    const int R0    = b * N_ + i0;                   // global row base

    if (tid < 64) {                                  // 2-way merge of sorted halves
        const size_t base = (size_t)(R0 + tid) * 2 * CAND;
        int p0 = 0, p1 = 0;
        #pragma unroll
        for (int o = 0; o < CAND; ++o) {
            const u32 k0 = candk[base + p0];
            const u32 k1 = candk[base + CAND + p1];
            if (k0 >= k1) { mj[tid * CAND + o] = candj[base + p0];        ++p0; }
            else          { mj[tid * CAND + o] = candj[base + CAND + p1]; ++p1; }
        }
    }
    __syncthreads();

    // fp64 rescore: quad (4 lanes) per dot; 128 quads x 6 rounds = 768 dots
    {
        const int q = tid >> 2, ql = tid & 3;        // quad 0..127, lane-in-quad
        const int r = q >> 1;                        // row 0..63 (2 quads per row)
        const float* qi = tok + (size_t)(R0 + r) * D_;
        const double di = invn[R0 + r];
        #pragma unroll 1
        for (int rr = 0; rr < 6; ++rr) {
            const int c = (q & 1) * 6 + rr;          // cand 0-5 / 6-11
            const int j = mj[r * CAND + c];
            const float* qj = tok + (size_t)(b * N_ + j) * D_;
            double s = 0.0;
            #pragma unroll 4
            for (int k = 0; k < 16; ++k) {
                const float4 x = *reinterpret_cast<const float4*>(qi + k * 16 + ql * 4);
                const float4 y = *reinterpret_cast<const float4*>(qj + k * 16 + ql * 4);
                s += (double)x.x * y.x + (double)x.y * y.y +
                     (double)x.z * y.z + (double)x.w * y.w;
            }
            s += __shfl_xor(s, 1, 64);
            s += __shfl_xor(s, 2, 64);
            if (ql == 0) dv[r * CAND + c] = s * di * invn[b * N_ + j];
        }
    }
    __syncthreads();

    // exact top-8 by fp64 rank (ties -> lower index, matching lax.top_k)
    if (tid < 64) {
        const int out_base = (R0 + tid) * K_;
        #pragma unroll 1
        for (int c = 0; c < CAND; ++c) {
            const double dc = dv[tid * CAND + c]; const int jc = mj[tid * CAND + c];
            int rank = 0;
            #pragma unroll 1
            for (int c2 = 0; c2 < CAND; ++c2) {
                if (c2 == c) continue;
                const double d2 = dv[tid * CAND + c2]; const int j2 = mj[tid * CAND + c2];
                if (d2 > dc || (d2 == dc && j2 < jc)) ++rank;
            }
            if (rank < K_) topk[out_base + rank] = jc;
        }
    }
}

// ------------- Kernel 3: mutual filter + scatter 1.0 -------------
__global__ __launch_bounds__(256) void mutual_kernel(const int* __restrict__ topk,
                                                     float* __restrict__ out) {
    const int gid = blockIdx.x * 256 + threadIdx.x;   // 32768*8 threads
    const int row = gid >> 3, s = gid & 7;
    const int j = topk[row * K_ + s];
    const int i = row & (N_ - 1);
    const int* tj = topk + ((row & ~(N_ - 1)) + j) * K_;
    bool m = false;
    #pragma unroll
    for (int u = 0; u < K_; ++u) m = m || (tj[u] == i);
    if (m) out[(size_t)row * N_ + j] = 1.0f;
}

extern "C" void kernel_launch(void* const* d_in, const int* in_sizes, int n_in,
                              void* d_out, int out_size, void* d_ws, size_t ws_size,
                              hipStream_t stream) {
    const float* tok = (const float*)d_in[0];
    float* out = (float*)d_out;
    double* invn = (double*)d_ws;                                  // 256 KB
    int* topk = (int*)((char*)d_ws + (size_t)B_ * N_ * sizeof(double)); // 1 MB
    // scratch lives in d_out (128 MB) until memset:
    //   [0,16MB) xhi, [16,32MB) xlo, [32,35MB) candk, [35,38MB) candj
    u16* xhi = (u16*)d_out;
    u16* xlo = xhi + (size_t)B_ * N_ * D_;
    u32* candk = (u32*)((char*)d_out + (size_t)32 * 1024 * 1024);
    int* candj = (int*)((char*)d_out + (size_t)35 * 1024 * 1024);

    prep_kernel<<<dim3(B_ * N_ / 4), 256, 0, stream>>>(tok, invn, xhi, xlo);
    sim_topk_kernel<<<dim3(1024), 256, 0, stream>>>(xhi, xlo, candk, candj);
    merge_rescore_kernel<<<dim3(B_ * N_ / 64), 512, 0, stream>>>(candk, candj, tok, invn, topk);
    hipMemsetAsync(d_out, 0, (size_t)out_size * sizeof(float), stream);
    mutual_kernel<<<dim3(B_ * N_ * K_ / 256), 256, 0, stream>>>(topk, out);
}

// Round 7
// 258.882 us; speedup vs baseline: 1.5198x; 1.1639x over previous
//
#include <hip/hip_runtime.h>
#include <math.h>
#include <stdint.h>

#define B_ 32
#define N_ 1024
#define D_ 256
#define K_ 8
#define CAND 12

typedef unsigned short u16;
typedef unsigned int u32;
typedef __attribute__((ext_vector_type(8))) short s16x8;   // 8 bf16 (4 VGPRs)
typedef __attribute__((ext_vector_type(16))) float f32x16; // 32x32 accumulator

__device__ inline void cp16(const void* g, void* l) {
    // async global->LDS, 16B/lane; LDS dest = wave-uniform base + lane*16
    __builtin_amdgcn_global_load_lds((const __attribute__((address_space(1))) void*)g,
                                     (__attribute__((address_space(3))) void*)l, 16, 0, 0);
}

__device__ inline u16 f2bf(float f) {               // RNE float->bf16 bits
    uint32_t u = __float_as_uint(f);
    return (u16)((u + 0x7fffu + ((u >> 16) & 1u)) >> 16);
}
__device__ inline u32 umax32(u32 a, u32 b) { return a > b ? a : b; }
__device__ inline u32 umin32(u32 a, u32 b) { return a < b ? a : b; }

// ------------- Kernel 1: fp64 inverse norms + normalized bf16 (hi only) -------------
// R7: xlo dropped -- candidate selection is hi-only (error sigma ~1e-4 << rank-8..12
// gaps ~7e-3..0.028); fp64 rescore remains the exact arbiter for the final top-8.
__global__ __launch_bounds__(256) void prep_kernel(const float* __restrict__ tok,
                                                   double* __restrict__ invn,
                                                   u16* __restrict__ xhi) {
    const int tid = threadIdx.x;
    const int wave = tid >> 6, lane = tid & 63;
    const int row = blockIdx.x * 4 + wave;          // 32768 rows
    const float4 v = *reinterpret_cast<const float4*>(tok + (size_t)row * D_ + lane * 4);
    double s = (double)v.x * v.x + (double)v.y * v.y +
               (double)v.z * v.z + (double)v.w * v.w;
    #pragma unroll
    for (int off = 32; off > 0; off >>= 1) s += __shfl_xor(s, off, 64);
    const double inv = 1.0 / (sqrt(s) + 1e-8);
    if (lane == 0) invn[row] = inv;
    ushort4 h;
    h.x = f2bf((float)(v.x * inv));
    h.y = f2bf((float)(v.y * inv));
    h.z = f2bf((float)(v.z * inv));
    h.w = f2bf((float)(v.w * inv));
    *reinterpret_cast<ushort4*>(xhi + (size_t)row * D_ + lane * 4) = h;
}

// ------------- Kernel 2: MFMA sim (hi-only) + in-register top-12 per j-half -------
// R7 structure: grid 1024 = 32 batches x 16 i-strips x 2 j-halves; 4 blocks/CU
// (exactly one dispatch pass). Per block: 64 i-rows x 8 jt. Hi-only => A frags are
// 64 VGPRs (was 128): total demand ~120 fits the (256,4) budget of 128 -> NO spill
// (R5/R6 lesson: spill shows as WRITE_SIZE balloon). B staging halves to 2 cp16/wave
// per round (vmcnt counts 2); LDS 16KB = 2 x 8KB B-hi buffers, XOR-swizzled.
// Swapped MFMA (mfma(B,A)): lane <-> i-row, reg <-> j; scan is register-only with
// packed u32 keys (24-bit monotone fp32 | (jt,reg) code), branchless max/min chain.
__global__ __launch_bounds__(256, 4) void sim_topk_kernel(const u16* __restrict__ Xhi,
                                                          u32* __restrict__ candk,
                                                          int* __restrict__ candj) {
    __shared__ __align__(16) char smem[16384];
    char* tiles = smem;                       // 2 bufs x 8KB (B hi)
    u32*  keysL = (u32*)smem;                 // 12.3KB alias after main loop

    // XCD batch-affinity swizzle: id&7 = XCD; each XCD owns 4 whole batches.
    const int id    = blockIdx.x;             // 0..1023
    const int chunk = id >> 3;                // 0..127
    const int b   = (id & 7) * 4 + (chunk >> 5);
    const int rem = chunk & 31;
    const int i0  = (rem >> 1) * 64;
    const int jh  = rem & 1;                  // j-half: jt in [jh*8, jh*8+8)

    const int tid = threadIdx.x;
    const int w = tid >> 6, lane = tid & 63;
    const int mq = w >> 1, nq = w & 1;        // 2x2 wave grid of 32x32 tiles
    const int half = lane >> 5;
    const int il = lane & 31;

    const u16* XhiB = Xhi + (size_t)b * N_ * D_;

    // staging: wave w covers rows w*16 + t*8 + srr (t=0,1); row&7 == srr
    const int srr = lane >> 3, spp = lane & 7;       // row-in-group, chunk-pos
    const int sgoff = (spp ^ srr) * 8;               // gathered source chunk (u16 units)
    const int srow  = w * 16 + srr;                  // + t*8

    // fragment rows (fixed per lane)
    const int ra = mq * 32 + il;
    const int rb = nq * 32 + il;
    const int xa = ra & 7, xb = rb & 7;              // XOR keys

    // ---- prologue: load A hi fragments (4kc x 4ks) into registers ----
    s16x8 Ahf[4][4];                                 // 64 regs, static-indexed only
    #pragma unroll
    for (int kc = 0; kc < 4; ++kc) {
        __syncthreads();                             // tiles free for overwrite
        #pragma unroll
        for (int t = 0; t < 2; ++t) {
            const int rr = srow + t * 8;
            cp16(XhiB + (size_t)(i0 + rr) * D_ + kc * 64 + sgoff,
                 tiles + w * 2048 + t * 1024);
        }
        __syncthreads();                             // vmcnt(0) drain ok in prologue
        #pragma unroll
        for (int ks = 0; ks < 4; ++ks) {
            const int ca = ((ks * 2 + half) ^ xa) * 16;
            Ahf[kc][ks] = *(const s16x8*)(tiles + ra * 128 + ca);
        }
    }
    __syncthreads();                                 // A reads done; clean vmcnt slate

    auto STAGE_B = [&](int round, int bufn) {        // round = (jt-jh*8)*4 + kc
        const int j0n = (jh * 8 + (round >> 2)) * 64;
        const int kcn = round & 3;
        char* bdst = tiles + bufn * 8192 + w * 2048;
        #pragma unroll
        for (int t = 0; t < 2; ++t) {
            const int rr = srow + t * 8;
            cp16(XhiB + (size_t)(j0n + rr) * D_ + kcn * 64 + sgoff, bdst + t * 1024);
        }
    };

    const int diag_jt = i0 >> 6;                     // jt where j-tile == i-strip
    u32 keys[CAND];
    #pragma unroll
    for (int c = 0; c < CAND; ++c) keys[c] = 0u;     // real sims always pack > 0

    STAGE_B(0, 0);

    for (int lt = 0; lt < 8; ++lt) {                 // local jt
        const int jt = jh * 8 + lt;
        f32x16 acc;
        #pragma unroll
        for (int c = 0; c < 16; ++c) acc[c] = 0.0f;

        #pragma unroll
        for (int kc = 0; kc < 4; ++kc) {
            const int r = lt * 4 + kc;
            const int cur = r & 1;
            // issue stage r+1 into the other buf; wait for round r's 2 loads
            if (r < 31) {
                STAGE_B(r + 1, cur ^ 1);
                asm volatile("s_waitcnt vmcnt(2)" ::: "memory");
            } else {
                asm volatile("s_waitcnt vmcnt(0)" ::: "memory");
            }
            __builtin_amdgcn_s_barrier();            // B1: all waves' round-r loads landed
            __builtin_amdgcn_sched_barrier(0);       // pin ds_reads below the barrier
            const char* bb = tiles + cur * 8192;
            #pragma unroll
            for (int ks = 0; ks < 4; ++ks) {
                const int cb = ((ks * 2 + half) ^ xb) * 16;
                const s16x8 bh = *(const s16x8*)(bb + rb * 128 + cb);
                acc = __builtin_amdgcn_mfma_f32_32x32x16_bf16(bh, Ahf[kc][ks], acc, 0, 0, 0);
            }
            __builtin_amdgcn_sched_barrier(0);       // pin reads/MFMA above B2
            __builtin_amdgcn_s_barrier();            // B2: buf[cur] free for stage r+2
        }

        // in-register scan (16 j-candidates of row i0+mq*32+il); overlaps next loads
        const u32 codebase = (u32)(jt << 4);         // jt<16, rg<16 -> 8-bit code
        const bool diag = (jt == diag_jt) && (mq == nq);
        #pragma unroll
        for (int rg = 0; rg < 16; ++rg) {
            const u32 u = __float_as_uint(acc[rg]);
            const u32 mono = u ^ ((u32)(((int)u) >> 31) | 0x80000000u); // order-preserving
            u32 key = (mono & 0xFFFFFF00u) | (codebase + (u32)rg);
            if (diag && ((rg & 3) + 8 * (rg >> 2) + 4 * half == il)) key = 0u; // kill self
            u32 t = key;
            #pragma unroll
            for (int c = 0; c < CAND; ++c) {         // branchless sorted insert (desc)
                const u32 hi = umax32(keys[c], t);
                t = umin32(keys[c], t);
                keys[c] = hi;
            }
        }
    }

    __syncthreads();                                 // tiles dead -> alias keysL
    {
        const int r = mq * 32 + il;
        const int s = nq * 2 + half;
        u32* dst = keysL + (r * 4 + s) * CAND;
        #pragma unroll
        for (int c = 0; c < CAND; ++c) dst[c] = keys[c];
    }
    __syncthreads();

    // 4-way merge of sorted slot lists -> this half's top-12 per row -> global scratch
    if (tid < 64) {
        const u32* kl = keysL + tid * (4 * CAND);
        const size_t base = ((size_t)(b * N_ + i0 + tid) * 2 + jh) * CAND;
        int p0 = 0, p1 = 0, p2 = 0, p3 = 0;
        #pragma unroll
        for (int o = 0; o < CAND; ++o) {
            const u32 k0v = kl[p0];
            const u32 k1v = kl[CAND + p1];
            const u32 k2v = kl[2 * CAND + p2];
            const u32 k3v = kl[3 * CAND + p3];
            int bg = 0; u32 bv = k0v;
            if (k1v > bv) { bv = k1v; bg = 1; }
            if (k2v > bv) { bv = k2v; bg = 2; }
            if (k3v > bv) { bv = k3v; bg = 3; }
            const int code = (int)(bv & 0xFFu);
            const int jtv = code >> 4, rg = code & 15;
            // j = jt*64 + nq*32 + (rg&3)+8*(rg>>2)+4*half; slot bg: nq=bg>>1, half=bg&1
            candk[base + o] = bv;
            candj[base + o] = jtv * 64 + (bg >> 1) * 32 + (rg & 3) + 8 * (rg >> 2)
                              + 4 * (bg & 1);
            p0 += (bg == 0); p1 += (bg == 1); p2 += (bg == 2); p3 += (bg == 3);
        }
    }
}

// ------------- Kernel 2b: merge halves + fp64 rescore + exact top-8 -------------
// R7: grid 512->1024 (32 rows/block): 4 quads/row x 3 rounds halves the dependent
// fp64 chain per thread and doubles block parallelism. XCD batch-affinity swizzle
// kept (R5 lesson: without it, FETCH explodes to 217MB).
__global__ __launch_bounds__(512) void merge_rescore_kernel(const u32* __restrict__ candk,
                                                            const int* __restrict__ candj,
                                                            const float* __restrict__ tok,
                                                            const double* __restrict__ invn,
                                                            int* __restrict__ topk) {
    __shared__ int    mj[32 * CAND];
    __shared__ double dv[32 * CAND];
    const int tid = threadIdx.x;

    // XCD batch-affinity swizzle: id&7 = XCD; each XCD owns 4 whole batches.
    const int id    = blockIdx.x;                    // 0..1023
    const int chunk = id >> 3;                       // 0..127
    const int b     = (id & 7) * 4 + (chunk >> 5);
    const int i0    = (chunk & 31) * 32;
    const int R0    = b * N_ + i0;                   // global row base (32 rows)

    if (tid < 32) {                                  // 2-way merge of sorted halves
        const size_t base = (size_t)(R0 + tid) * 2 * CAND;
        int p0 = 0, p1 = 0;
        #pragma unroll
        for (int o = 0; o < CAND; ++o) {
            const u32 k0 = candk[base + p0];
            const u32 k1 = candk[base + CAND + p1];
            if (k0 >= k1) { mj[tid * CAND + o] = candj[base + p0];        ++p0; }
            else          { mj[tid * CAND + o] = candj[base + CAND + p1]; ++p1; }
        }
    }
    __syncthreads();

    // fp64 rescore: quad (4 lanes) per dot; 128 quads, 4 quads/row, 3 rounds
    {
        const int q = tid >> 2, ql = tid & 3;        // quad 0..127, lane-in-quad
        const int r = q >> 2;                        // row 0..31
        const float* qi = tok + (size_t)(R0 + r) * D_;
        const double di = invn[R0 + r];
        #pragma unroll 1
        for (int rr = 0; rr < 3; ++rr) {
            const int c = (q & 3) * 3 + rr;          // cand 0..11
            const int j = mj[r * CAND + c];
            const float* qj = tok + (size_t)(b * N_ + j) * D_;
            double s = 0.0;
            #pragma unroll 4
            for (int k = 0; k < 16; ++k) {
                const float4 x = *reinterpret_cast<const float4*>(qi + k * 16 + ql * 4);
                const float4 y = *reinterpret_cast<const float4*>(qj + k * 16 + ql * 4);
                s += (double)x.x * y.x + (double)x.y * y.y +
                     (double)x.z * y.z + (double)x.w * y.w;
            }
            s += __shfl_xor(s, 1, 64);
            s += __shfl_xor(s, 2, 64);
            if (ql == 0) dv[r * CAND + c] = s * di * invn[b * N_ + j];
        }
    }
    __syncthreads();

    // exact top-8 by fp64 rank (ties -> lower index, matching lax.top_k)
    if (tid < 32) {
        const int out_base = (R0 + tid) * K_;
        #pragma unroll 1
        for (int c = 0; c < CAND; ++c) {
            const double dc = dv[tid * CAND + c]; const int jc = mj[tid * CAND + c];
            int rank = 0;
            #pragma unroll 1
            for (int c2 = 0; c2 < CAND; ++c2) {
                if (c2 == c) continue;
                const double d2 = dv[tid * CAND + c2]; const int j2 = mj[tid * CAND + c2];
                if (d2 > dc || (d2 == dc && j2 < jc)) ++rank;
            }
            if (rank < K_) topk[out_base + rank] = jc;
        }
    }
}

// ------------- Kernel 3: mutual filter + scatter 1.0 -------------
__global__ __launch_bounds__(256) void mutual_kernel(const int* __restrict__ topk,
                                                     float* __restrict__ out) {
    const int gid = blockIdx.x * 256 + threadIdx.x;   // 32768*8 threads
    const int row = gid >> 3, s = gid & 7;
    const int j = topk[row * K_ + s];
    const int i = row & (N_ - 1);
    const int* tj = topk + ((row & ~(N_ - 1)) + j) * K_;
    bool m = false;
    #pragma unroll
    for (int u = 0; u < K_; ++u) m = m || (tj[u] == i);
    if (m) out[(size_t)row * N_ + j] = 1.0f;
}

extern "C" void kernel_launch(void* const* d_in, const int* in_sizes, int n_in,
                              void* d_out, int out_size, void* d_ws, size_t ws_size,
                              hipStream_t stream) {
    const float* tok = (const float*)d_in[0];
    float* out = (float*)d_out;
    double* invn = (double*)d_ws;                                  // 256 KB
    int* topk = (int*)((char*)d_ws + (size_t)B_ * N_ * sizeof(double)); // 1 MB
    // scratch lives in d_out (128 MB) until memset:
    //   [0,16MB) xhi, [32,35MB) candk, [35,38MB) candj
    u16* xhi = (u16*)d_out;
    u32* candk = (u32*)((char*)d_out + (size_t)32 * 1024 * 1024);
    int* candj = (int*)((char*)d_out + (size_t)35 * 1024 * 1024);

    prep_kernel<<<dim3(B_ * N_ / 4), 256, 0, stream>>>(tok, invn, xhi);
    sim_topk_kernel<<<dim3(1024), 256, 0, stream>>>(xhi, candk, candj);
    merge_rescore_kernel<<<dim3(B_ * N_ / 32), 512, 0, stream>>>(candk, candj, tok, invn, topk);
    hipMemsetAsync(d_out, 0, (size_t)out_size * sizeof(float), stream);
    mutual_kernel<<<dim3(B_ * N_ * K_ / 256), 256, 0, stream>>>(topk, out);
}